// Round 2
// baseline (269.416 us; speedup 1.0000x reference)
//
#include <hip/hip_runtime.h>
#include <math.h>

// LSTM B=1024,T=512,IN=16,H=64,OUT=8, gates i,f,g,o.
// R14: DE-REPLICATION. R13 analysis: step = 1060cyc, issue-bound across
// pipes summed over 2 in-phase co-resident blocks; MFMA pipe ~495cyc/SIMD/
// step because 16 B-cols carried only 2 real batches (8x replication).
//   1) BT=4: cols = 4 batches x 4 replicas; lane owns unique (b=m&3,
//      r=m>>2, j=16w+4q+r). 256 blocks -> 1 block/CU, 1 wave/SIMD:
//      per-SIMD MFMA issue 495 -> 165 (on-chain), no partner contention.
//   2) gate-pairing dropped (m^8 bit now carries b/r); 10 trans/step but
//      only 1 wave/SIMD -> trans pipe 160cyc < 2x96 before.
//   3) all 64 lanes valid -> no dump/exec-mask; HSTRIDE=80 (batch stride
//      160B = 40 dwords = +8 banks): h-write = 32 dwords/32 banks
//      CONFLICT-FREE (R13's 10.5M conflicts came from the dump aliasing).
//   4) x-part MFMAs (accX = x_t+1 @ W_ih + bias) seeded during step t's
//      activation phase -> off the critical chain; h-MFMA consumes accX
//      as C-in directly.
// Kept: fp16 weights pinned with act scales folded (i,f,o x -L2E, g x
// +L2E2, cell pre-scaled cs=L2E2*c), dbuf h in LDS, 1 lite barrier/step,
// x prefetched ~3 steps ahead.

#define LSTM_T 512
#define LSTM_IN 16
#define LSTM_H 64
#define LSTM_OUT 8
#define BT 4
#define HSTRIDE 80   // halves per batch row: 64 h + 16 pad; 160B stride = +8 banks

#define L2E   1.44269504088896340736f
#define L2E2  2.88539008177792681472f

typedef _Float16 half8  __attribute__((ext_vector_type(8)));
typedef float    floatx4 __attribute__((ext_vector_type(4)));

static __device__ __forceinline__ float fast_rcp(float x) { return __builtin_amdgcn_rcpf(x); }
static __device__ __forceinline__ float fast_exp2(float x) { return __builtin_amdgcn_exp2f(x); }
// p pre-scaled by log2e:
static __device__ __forceinline__ float sigm2(float p) { return fast_rcp(1.0f + fast_exp2(-p)); }
static __device__ __forceinline__ void pin4(int4& v) {
    asm volatile("" : "+v"(v.x), "+v"(v.y), "+v"(v.z), "+v"(v.w));
}
static __device__ __forceinline__ void pinf4(float4& v) {
    asm volatile("" : "+v"(v.x), "+v"(v.y), "+v"(v.z), "+v"(v.w));
}
static __device__ __forceinline__ void lite_barrier() {
    asm volatile("s_waitcnt lgkmcnt(0)\n\ts_barrier" ::: "memory");
}
static __device__ __forceinline__ unsigned pk2h(float a, float b) {
    return __builtin_bit_cast(unsigned, __builtin_amdgcn_cvt_pkrtz(a, b));
}
static __device__ __forceinline__ half8 to_h8(float4 a, float4 b) {
    uint4 u = make_uint4(pk2h(a.x, a.y), pk2h(a.z, a.w), pk2h(b.x, b.y), pk2h(b.z, b.w));
    return __builtin_bit_cast(half8, u);
}
static __device__ __forceinline__ int4 cvt8h(float4 a, float4 b) {
    return __builtin_bit_cast(int4, to_h8(a, b));
}
static __device__ __forceinline__ float4 ld4(const float* p) {
    return *reinterpret_cast<const float4*>(p);
}
static __device__ __forceinline__ float4 scl4(float4 v, float s) {
    return make_float4(s * v.x, s * v.y, s * v.z, s * v.w);
}
static __device__ __forceinline__ float sel4(floatx4 v, bool r0, bool r1) {
    float lo = r0 ? v[1] : v[0];
    float hi = r0 ? v[3] : v[2];
    return r1 ? hi : lo;
}

__global__ __launch_bounds__(256, 1)
void lstm_mfma_kernel(const float* __restrict__ x,
                      const float* __restrict__ W_ih,
                      const float* __restrict__ W_hh,
                      const float* __restrict__ b_ih,
                      const float* __restrict__ b_hh,
                      const float* __restrict__ W_fc,
                      const float* __restrict__ b_fc,
                      float* __restrict__ out) {
    const int tid   = threadIdx.x;
    const int lane  = tid & 63;
    const int w     = tid >> 6;        // wave -> j-slice [16w, 16w+16)
    const int q     = lane >> 4;       // k-quad / C row group
    const int m     = lane & 15;       // A row-in-tile / B col / C col
    const int b     = m & 3;           // real batch (cols = 4 b x 4 replicas)
    const int r     = m >> 2;          // replica id -> C reg r to activate
    const bool r0   = (r & 1) != 0;
    const bool r1   = (r & 2) != 0;
    const int jmine = 16 * w + 4 * q + r;   // this lane's hidden index
    const int bbase = blockIdx.x * BT;

    __shared__ __align__(128) _Float16 hbuf[2][BT][HSTRIDE]; // h state, dbuf
    __shared__ __align__(16)  float    hfin[BT][LSTM_H];     // final h for FC

    // ---- weights as pinned fp16 A-fragments, act scales PRE-FOLDED ----
    // tile tt = gate type (0=i,1=f,2=g,3=o); A row = tt*64 + 16w + m.
    int4 Ah[4][2], Ax[4];
    float4 bias4[4];
    #pragma unroll
    for (int tt = 0; tt < 4; ++tt) {
        const float sc = (tt == 2) ? L2E2 : -L2E;
        const int gt = tt * 64 + 16 * w + m;
        #pragma unroll
        for (int c = 0; c < 2; ++c) {
            const float* s = W_hh + gt * LSTM_H + 32 * c + 8 * q;
            Ah[tt][c] = cvt8h(scl4(ld4(s), sc), scl4(ld4(s + 4), sc));
            pin4(Ah[tt][c]);
        }
        float4 xa = make_float4(0.f, 0.f, 0.f, 0.f), xb = xa;
        if (q < 2) {
            const float* s = W_ih + gt * LSTM_IN + 8 * q;
            xa = ld4(s); xb = ld4(s + 4);
        }
        Ax[tt] = cvt8h(scl4(xa, sc), scl4(xb, sc));
        pin4(Ax[tt]);
        const int gb = tt * 64 + 16 * w + 4 * q;
        float4 bi = ld4(b_ih + gb), bh = ld4(b_hh + gb);
        bias4[tt] = make_float4(sc * (bi.x + bh.x), sc * (bi.y + bh.y),
                                sc * (bi.z + bh.z), sc * (bi.w + bh.w));
        pinf4(bias4[tt]);
    }

    // ---- zero hbuf[0] h-region (h_{-1} = 0): 4 batches * 64 halves ----
    if (tid < 128) {
        int bb = tid >> 5, jj = tid & 31;
        reinterpret_cast<int*>(&hbuf[0][bb][0])[jj] = 0;
    }

    // ---- x: lane covers batch b, elements 8q..8q+7 (q<2 real) ----
    const float* xp = x + (size_t)(bbase + b) * LSTM_T * LSTM_IN + 8 * q;
    float4 xA0 = make_float4(0.f, 0.f, 0.f, 0.f), xA1 = xA0;  // even steps
    float4 xB0 = xA0, xB1 = xA0;                              // odd steps
    if (q < 2) {
        xA0 = ld4(xp);              xA1 = ld4(xp + 4);               // x_0
        xB0 = ld4(xp + LSTM_IN);    xB1 = ld4(xp + LSTM_IN + 4);     // x_1
    }

    // ---- seed accX with x_0 contribution + bias (h-independent) ----
    floatx4 accX[4];
    {
        half8 xf = to_h8(xA0, xA1);
        #pragma unroll
        for (int tt = 0; tt < 4; ++tt)
            accX[tt] = __builtin_amdgcn_mfma_f32_16x16x32_f16(
                __builtin_bit_cast(half8, Ax[tt]), xf,
                __builtin_bit_cast(floatx4, bias4[tt]), 0, 0, 0);
    }
    if (q < 2) {       // reload even-slot with x_2
        xA0 = ld4(xp + 2 * LSTM_IN);
        xA1 = ld4(xp + 2 * LSTM_IN + 4);
    }
    __syncthreads();   // hbuf zeros visible

    float cs = 0.0f, hreg = 0.0f;   // cs = L2E2 * c (pre-scaled cell)

#define STEP(T_, X0, X1)                                                        \
    {                                                                           \
        const _Float16* cur = &hbuf[(T_) & 1][0][0];                            \
        _Float16*       nxt = &hbuf[((T_) + 1) & 1][0][0];                      \
        /* h_{t-1} B-frags (col m -> batch b): the only on-chain loads */       \
        half8 bh0 = *reinterpret_cast<const half8*>(cur + b * HSTRIDE + 8 * q); \
        half8 bh1 = *reinterpret_cast<const half8*>(cur + b * HSTRIDE + 32 + 8 * q); \
        floatx4 acc[4];                                                         \
        _Pragma("unroll")                                                       \
        for (int tt = 0; tt < 4; ++tt)                                          \
            acc[tt] = __builtin_amdgcn_mfma_f32_16x16x32_f16(                   \
                __builtin_bit_cast(half8, Ah[tt][0]), bh0, accX[tt], 0, 0, 0);  \
        _Pragma("unroll")                                                       \
        for (int tt = 0; tt < 4; ++tt)                                          \
            acc[tt] = __builtin_amdgcn_mfma_f32_16x16x32_f16(                   \
                __builtin_bit_cast(half8, Ah[tt][1]), bh1, acc[tt], 0, 0, 0);   \
        /* seed accX for t+1 (x-part + bias): h-independent, hides under   */   \
        /* the activation chain on the matrix pipe                          */  \
        if ((T_) + 1 < LSTM_T) {                                                \
            half8 xf = to_h8(X0, X1);                                           \
            _Pragma("unroll")                                                   \
            for (int tt = 0; tt < 4; ++tt)                                      \
                accX[tt] = __builtin_amdgcn_mfma_f32_16x16x32_f16(              \
                    __builtin_bit_cast(half8, Ax[tt]), xf,                      \
                    __builtin_bit_cast(floatx4, bias4[tt]), 0, 0, 0);           \
        }                                                                       \
        /* reload this x reg set with x_{t+3} */                                \
        if (q < 2 && (T_) + 3 < LSTM_T) {                                       \
            X0 = ld4(xp + (size_t)((T_) + 3) * LSTM_IN);                        \
            X1 = ld4(xp + (size_t)((T_) + 3) * LSTM_IN + 4);                    \
        }                                                                       \
        /* activations: scales pre-folded into weights */                       \
        float ui = sel4(acc[0], r0, r1);                                        \
        float uf = sel4(acc[1], r0, r1);                                        \
        float ug = sel4(acc[2], r0, r1);                                        \
        float uo = sel4(acc[3], r0, r1);                                        \
        float ff = fast_rcp(1.0f + fast_exp2(uf));                              \
        float ii = fast_rcp(1.0f + fast_exp2(ui));                              \
        float gg = fmaf(-2.0f, fast_rcp(1.0f + fast_exp2(ug)), 1.0f);           \
        float oo = fast_rcp(1.0f + fast_exp2(uo));                              \
        cs = fmaf(ff, cs, (L2E2 * ii) * gg);                                    \
        float th = fmaf(-2.0f, fast_rcp(1.0f + fast_exp2(cs)), 1.0f);           \
        hreg = oo * th;                                                         \
        /* conflict-free write: 64 lanes -> 32 dwords / 32 banks */             \
        nxt[b * HSTRIDE + jmine] = (_Float16)hreg;                              \
        lite_barrier();                                                         \
    }

    for (int t = 0; t < LSTM_T; t += 2) {
        STEP(t,     xB0, xB1)   // seeds with x_{t+1}
        STEP(t + 1, xA0, xA1)   // seeds with x_{t+2}
    }
#undef STEP

    // ---- final h (fp32) -> LDS, then FC + sigmoid ----
    hfin[b][jmine] = hreg;
    __syncthreads();

    if (tid < BT * LSTM_OUT) {
        int bb = tid >> 3, o = tid & 7;
        float s = b_fc[o];
        #pragma unroll
        for (int j4 = 0; j4 < LSTM_H / 4; ++j4) {
            float4 wv = ld4(W_fc + o * LSTM_H + 4 * j4);
            float4 hv = *reinterpret_cast<const float4*>(&hfin[bb][4 * j4]);
            s = fmaf(wv.x, hv.x, s);
            s = fmaf(wv.y, hv.y, s);
            s = fmaf(wv.z, hv.z, s);
            s = fmaf(wv.w, hv.w, s);
        }
        out[(size_t)(bbase + bb) * LSTM_OUT + o] = sigm2(s * L2E);
    }
}

extern "C" void kernel_launch(void* const* d_in, const int* in_sizes, int n_in,
                              void* d_out, int out_size, void* d_ws, size_t ws_size,
                              hipStream_t stream) {
    const float* x    = (const float*)d_in[0];
    const float* W_ih = (const float*)d_in[1];
    const float* W_hh = (const float*)d_in[2];
    const float* b_ih = (const float*)d_in[3];
    const float* b_hh = (const float*)d_in[4];
    const float* W_fc = (const float*)d_in[5];
    const float* b_fc = (const float*)d_in[6];
    float* out = (float*)d_out;

    lstm_mfma_kernel<<<1024 / BT, 256, 0, stream>>>(
        x, W_ih, W_hh, b_ih, b_hh, W_fc, b_fc, out);
}

// Round 3
// 257.058 us; speedup vs baseline: 1.0481x; 1.0481x over previous
//
#include <hip/hip_runtime.h>
#include <math.h>

// LSTM B=1024,T=512,IN=16,H=64,OUT=8, gates i,f,g,o.
// R15: MIN-ISSUE CHAIN. R14 proved step-time = single-wave in-order issue
// + dep stalls (halving pipe contention changed nothing; chain ~1120cyc).
// Budget: 12 MFMA ~190, trans 10x16=160, VALU ~100, LDS RT ~200, barrier.
// So: shrink the wave's on-chain instruction stream.
//   1) BT=2 + gate-pairing restored (trans 10 -> 6/step): half0 (m<8)
//      computes sigma(f),sigma(i); half1 computes tanh(g),sigma(o); DPP
//      row_ror:8 exchanges (VALU, not LDS pipe).
//   2) SYMMETRIC halves: row_ror:8 swaps both ways and the value sets are
//      symmetric, so BOTH halves compute identical valid cs/h via 4
//      cndmask. -> unconditional ds_write, pair lanes write the SAME b16
//      address with the SAME value (merge, conflict-free; no dump region
//      (R13's 10.5M-conflict bug), no exec toggle). HSTRIDE=80 keeps
//      b0/b1 bank octaves disjoint.
//   3) MFMA order f,g tiles first: u1 sel+exp2 issues while i,o MFMAs and
//      accX seed fill the matrix pipe (trans latency hides MFMA issue).
//   4) accX (x@W_ih + bias for t+1) seeded in the trans shadow (R14),
//      h-MFMA consumes accX as C-in.
//   5) setprio(1) over the serial trans tail only (wins arbitration vs
//      partner block's MFMA phase; 2 blocks/CU).
// Kept: fp16 weights pinned, act scales folded (i,f,o x -L2E, g x +L2E2,
// cs = L2E2*c), dbuf h LDS, 1 lite barrier/step, x prefetch 3 ahead.

#define LSTM_T 512
#define LSTM_IN 16
#define LSTM_H 64
#define LSTM_OUT 8
#define BT 2
#define HSTRIDE 80   // halves per batch row; 160B stride = +8 banks

#define L2E   1.44269504088896340736f
#define L2E2  2.88539008177792681472f

typedef _Float16 half8  __attribute__((ext_vector_type(8)));
typedef float    floatx4 __attribute__((ext_vector_type(4)));

static __device__ __forceinline__ float fast_rcp(float x) { return __builtin_amdgcn_rcpf(x); }
static __device__ __forceinline__ float fast_exp2(float x) { return __builtin_amdgcn_exp2f(x); }
// p pre-scaled by log2e:
static __device__ __forceinline__ float sigm2(float p) { return fast_rcp(1.0f + fast_exp2(-p)); }
static __device__ __forceinline__ void pin4(int4& v) {
    asm volatile("" : "+v"(v.x), "+v"(v.y), "+v"(v.z), "+v"(v.w));
}
static __device__ __forceinline__ void pinf4(float4& v) {
    asm volatile("" : "+v"(v.x), "+v"(v.y), "+v"(v.z), "+v"(v.w));
}
static __device__ __forceinline__ void lite_barrier() {
    asm volatile("s_waitcnt lgkmcnt(0)\n\ts_barrier" ::: "memory");
}
static __device__ __forceinline__ unsigned pk2h(float a, float b) {
    return __builtin_bit_cast(unsigned, __builtin_amdgcn_cvt_pkrtz(a, b));
}
static __device__ __forceinline__ half8 to_h8(float4 a, float4 b) {
    uint4 u = make_uint4(pk2h(a.x, a.y), pk2h(a.z, a.w), pk2h(b.x, b.y), pk2h(b.z, b.w));
    return __builtin_bit_cast(half8, u);
}
static __device__ __forceinline__ int4 cvt8h(float4 a, float4 b) {
    return __builtin_bit_cast(int4, to_h8(a, b));
}
static __device__ __forceinline__ float4 ld4(const float* p) {
    return *reinterpret_cast<const float4*>(p);
}
static __device__ __forceinline__ float4 scl4(float4 v, float s) {
    return make_float4(s * v.x, s * v.y, s * v.z, s * v.w);
}
static __device__ __forceinline__ float sel4(floatx4 v, bool r0, bool r1) {
    float lo = r0 ? v[1] : v[0];
    float hi = r0 ? v[3] : v[2];
    return r1 ? hi : lo;
}
// exchange with lane^8 via DPP row_ror:8 (16-lane rows): two-way swap,
// full-rate VALU, no LDS pipe, no lgkmcnt involvement.
static __device__ __forceinline__ float dpp8(float v) {
    int r = __builtin_amdgcn_update_dpp(0, __builtin_bit_cast(int, v),
                                        0x128, 0xF, 0xF, false);
    return __builtin_bit_cast(float, r);
}

__global__ __launch_bounds__(256, 2)
void lstm_mfma_kernel(const float* __restrict__ x,
                      const float* __restrict__ W_ih,
                      const float* __restrict__ W_hh,
                      const float* __restrict__ b_ih,
                      const float* __restrict__ b_hh,
                      const float* __restrict__ W_fc,
                      const float* __restrict__ b_fc,
                      float* __restrict__ out) {
    const int tid   = threadIdx.x;
    const int lane  = tid & 63;
    const int w     = tid >> 6;        // wave -> j-slice [16w, 16w+16)
    const int q     = lane >> 4;       // k-quad / C row group
    const int m     = lane & 15;       // A row-in-tile / B col / C col
    const int b     = m & 1;           // real batch (cols = 2 b x 8 replicas)
    const int rho   = (m >> 1) & 3;    // replica id -> C row r to activate
    const bool r0   = (rho & 1) != 0;
    const bool r1   = (rho & 2) != 0;
    const bool h1   = (m & 8) != 0;    // gate-pair half: 0 = f/i, 1 = g/o
    const int jmine = 16 * w + 4 * q + rho;   // this lane's hidden index
    const int bbase = blockIdx.x * BT;

    // unified activation: act1 = a1 + b1*rcp(1+exp2(u1)), scales pre-folded
    // in weights: half0 u1 = -L2E*f_pre (sigma); half1 u1 = L2E2*g_pre (tanh)
    const float a1 = h1 ? 1.0f : 0.0f;
    const float b1 = h1 ? -2.0f : 1.0f;

    __shared__ __align__(128) _Float16 hbuf[2][BT][HSTRIDE]; // h state, dbuf
    __shared__ __align__(16)  float    hfin[BT][LSTM_H];     // final h for FC

    // ---- weights as pinned fp16 A-fragments, act scales PRE-FOLDED ----
    // tile tt = gate type (0=i,1=f,2=g,3=o); A row = tt*64 + 16w + m.
    int4 Ah[4][2], Ax[4];
    float4 bias4[4];
    #pragma unroll
    for (int tt = 0; tt < 4; ++tt) {
        const float sc = (tt == 2) ? L2E2 : -L2E;
        const int gt = tt * 64 + 16 * w + m;
        #pragma unroll
        for (int c = 0; c < 2; ++c) {
            const float* s = W_hh + gt * LSTM_H + 32 * c + 8 * q;
            Ah[tt][c] = cvt8h(scl4(ld4(s), sc), scl4(ld4(s + 4), sc));
            pin4(Ah[tt][c]);
        }
        float4 xa = make_float4(0.f, 0.f, 0.f, 0.f), xb = xa;
        if (q < 2) {
            const float* s = W_ih + gt * LSTM_IN + 8 * q;
            xa = ld4(s); xb = ld4(s + 4);
        }
        Ax[tt] = cvt8h(scl4(xa, sc), scl4(xb, sc));
        pin4(Ax[tt]);
        const int gb = tt * 64 + 16 * w + 4 * q;
        float4 bi = ld4(b_ih + gb), bh = ld4(b_hh + gb);
        bias4[tt] = make_float4(sc * (bi.x + bh.x), sc * (bi.y + bh.y),
                                sc * (bi.z + bh.z), sc * (bi.w + bh.w));
        pinf4(bias4[tt]);
    }

    // ---- zero hbuf[0] (h_{-1} = 0): 2 batches * 80 halves = 80 dwords ----
    if (tid < 80) {
        reinterpret_cast<int*>(&hbuf[0][0][0])[tid] = 0;
    }

    // ---- x: lane covers batch b, elements 8q..8q+7 (q<2 real) ----
    const float* xp = x + (size_t)(bbase + b) * LSTM_T * LSTM_IN + 8 * q;
    float4 xA0 = make_float4(0.f, 0.f, 0.f, 0.f), xA1 = xA0;  // even slots
    float4 xB0 = xA0, xB1 = xA0;                              // odd slots
    if (q < 2) {
        xA0 = ld4(xp);              xA1 = ld4(xp + 4);               // x_0
        xB0 = ld4(xp + LSTM_IN);    xB1 = ld4(xp + LSTM_IN + 4);     // x_1
    }

    // ---- seed accX with x_0 contribution + bias (h-independent) ----
    floatx4 accX[4];
    {
        half8 xf = to_h8(xA0, xA1);
        #pragma unroll
        for (int tt = 0; tt < 4; ++tt)
            accX[tt] = __builtin_amdgcn_mfma_f32_16x16x32_f16(
                __builtin_bit_cast(half8, Ax[tt]), xf,
                __builtin_bit_cast(floatx4, bias4[tt]), 0, 0, 0);
    }
    if (q < 2) {       // reload even slot with x_2
        xA0 = ld4(xp + 2 * LSTM_IN);
        xA1 = ld4(xp + 2 * LSTM_IN + 4);
    }
    __syncthreads();   // hbuf zeros visible

    float cs = 0.0f, hreg = 0.0f;   // cs = L2E2 * c (pre-scaled cell)

#define STEP(T_, X0, X1)                                                        \
    {                                                                           \
        const _Float16* cur = &hbuf[(T_) & 1][0][0];                            \
        _Float16*       nxt = &hbuf[((T_) + 1) & 1][0][0];                      \
        /* h_{t-1} B-frags (col m -> batch b): the only on-chain loads */       \
        half8 bh0 = *reinterpret_cast<const half8*>(cur + b * HSTRIDE + 8 * q); \
        half8 bh1 = *reinterpret_cast<const half8*>(cur + b * HSTRIDE + 32 + 8 * q); \
        /* f,g tiles FIRST: their activation chain overlaps i,o MFMAs */        \
        floatx4 accf, accg, acci, acco;                                         \
        accf = __builtin_amdgcn_mfma_f32_16x16x32_f16(                          \
            __builtin_bit_cast(half8, Ah[1][0]), bh0, accX[1], 0, 0, 0);        \
        accg = __builtin_amdgcn_mfma_f32_16x16x32_f16(                          \
            __builtin_bit_cast(half8, Ah[2][0]), bh0, accX[2], 0, 0, 0);        \
        accf = __builtin_amdgcn_mfma_f32_16x16x32_f16(                          \
            __builtin_bit_cast(half8, Ah[1][1]), bh1, accf, 0, 0, 0);           \
        accg = __builtin_amdgcn_mfma_f32_16x16x32_f16(                          \
            __builtin_bit_cast(half8, Ah[2][1]), bh1, accg, 0, 0, 0);           \
        __builtin_amdgcn_s_setprio(1);                                          \
        float uf = sel4(accf, r0, r1);                                          \
        float ug = sel4(accg, r0, r1);                                          \
        float u1 = h1 ? ug : uf;                                                \
        float e1 = fast_exp2(u1);                                               \
        acci = __builtin_amdgcn_mfma_f32_16x16x32_f16(                          \
            __builtin_bit_cast(half8, Ah[0][0]), bh0, accX[0], 0, 0, 0);        \
        acco = __builtin_amdgcn_mfma_f32_16x16x32_f16(                          \
            __builtin_bit_cast(half8, Ah[3][0]), bh0, accX[3], 0, 0, 0);        \
        acci = __builtin_amdgcn_mfma_f32_16x16x32_f16(                          \
            __builtin_bit_cast(half8, Ah[0][1]), bh1, acci, 0, 0, 0);           \
        acco = __builtin_amdgcn_mfma_f32_16x16x32_f16(                          \
            __builtin_bit_cast(half8, Ah[3][1]), bh1, acco, 0, 0, 0);           \
        float ui = sel4(acci, r0, r1);                                          \
        float uo = sel4(acco, r0, r1);                                          \
        float u2 = h1 ? uo : ui;                                                \
        float e2 = fast_exp2(u2);                                               \
        /* seed accX for t+1 (x-part + bias) inside the trans shadow */         \
        if ((T_) + 1 < LSTM_T) {                                                \
            half8 xf = to_h8(X0, X1);                                           \
            _Pragma("unroll")                                                   \
            for (int tt = 0; tt < 4; ++tt)                                      \
                accX[tt] = __builtin_amdgcn_mfma_f32_16x16x32_f16(              \
                    __builtin_bit_cast(half8, Ax[tt]), xf,                      \
                    __builtin_bit_cast(floatx4, bias4[tt]), 0, 0, 0);           \
        }                                                                       \
        /* reload this x reg set with x_{t+3} */                                \
        if (q < 2 && (T_) + 3 < LSTM_T) {                                       \
            X0 = ld4(xp + (size_t)((T_) + 3) * LSTM_IN);                        \
            X1 = ld4(xp + (size_t)((T_) + 3) * LSTM_IN + 4);                    \
        }                                                                       \
        /* unified act: half0 -> sigma(f),sigma(i); half1 -> tanh(g),sigma(o) */\
        float act1 = fmaf(b1, fast_rcp(1.0f + e1), a1);                         \
        float act2 = fast_rcp(1.0f + e2);                                       \
        /* two-way DPP swap with lane^8 */                                      \
        float g_in = dpp8(act1);                                                \
        float o_in = dpp8(act2);                                                \
        /* symmetric roles: both halves compute identical valid cs/h */         \
        float fsel = h1 ? g_in : act1;   /* sigma(f) */                         \
        float isel = h1 ? o_in : act2;   /* sigma(i) */                         \
        float gsel = h1 ? act1 : g_in;   /* tanh(g)  */                         \
        float osel = h1 ? act2 : o_in;   /* sigma(o) */                         \
        cs = fmaf(fsel, cs, (L2E2 * isel) * gsel);                              \
        float th = fmaf(-2.0f, fast_rcp(1.0f + fast_exp2(cs)), 1.0f);           \
        hreg = osel * th;                                                       \
        /* unconditional write: pair lanes hit the same b16 addr with the  */   \
        /* same value (merge). Banks: b0 octave 8w.., b1 octave 8w+8..     */   \
        nxt[b * HSTRIDE + jmine] = (_Float16)hreg;                              \
        __builtin_amdgcn_s_setprio(0);                                          \
        lite_barrier();                                                         \
    }

    for (int t = 0; t < LSTM_T; t += 2) {
        STEP(t,     xB0, xB1)   // seeds accX with x_{t+1}
        STEP(t + 1, xA0, xA1)   // seeds accX with x_{t+2}
    }
#undef STEP

    // ---- final h (fp32) -> LDS, then FC + sigmoid ----
    hfin[b][jmine] = hreg;      // pair lanes write same value
    __syncthreads();

    if (tid < BT * LSTM_OUT) {
        int bb = tid >> 3, o = tid & 7;
        float s = b_fc[o];
        #pragma unroll
        for (int j4 = 0; j4 < LSTM_H / 4; ++j4) {
            float4 wv = ld4(W_fc + o * LSTM_H + 4 * j4);
            float4 hv = *reinterpret_cast<const float4*>(&hfin[bb][4 * j4]);
            s = fmaf(wv.x, hv.x, s);
            s = fmaf(wv.y, hv.y, s);
            s = fmaf(wv.z, hv.z, s);
            s = fmaf(wv.w, hv.w, s);
        }
        out[(size_t)(bbase + bb) * LSTM_OUT + o] = sigm2(s * L2E);
    }
}

extern "C" void kernel_launch(void* const* d_in, const int* in_sizes, int n_in,
                              void* d_out, int out_size, void* d_ws, size_t ws_size,
                              hipStream_t stream) {
    const float* x    = (const float*)d_in[0];
    const float* W_ih = (const float*)d_in[1];
    const float* W_hh = (const float*)d_in[2];
    const float* b_ih = (const float*)d_in[3];
    const float* b_hh = (const float*)d_in[4];
    const float* W_fc = (const float*)d_in[5];
    const float* b_fc = (const float*)d_in[6];
    float* out = (float*)d_out;

    lstm_mfma_kernel<<<1024 / BT, 256, 0, stream>>>(
        x, W_ih, W_hh, b_ih, b_hh, W_fc, b_fc, out);
}